// Round 10
// baseline (431.159 us; speedup 1.0000x reference)
//
#include <hip/hip_runtime.h>
#include <hip/hip_bf16.h>
#include <math.h>

#define N_NODES 50000
#define N_EDGES 400000
#define HEADS 6
#define DIMS 32
#define FEAT 192
#define NEG_SLOPE 0.2f

typedef __attribute__((ext_vector_type(8))) short short8;
typedef __attribute__((ext_vector_type(4))) float f32x4;

__device__ __forceinline__ unsigned short f2bu(float f) {
    __hip_bfloat16 h = __float2bfloat16(f);
    unsigned short u; __builtin_memcpy(&u, &h, 2); return u;
}
__device__ __forceinline__ float bu2f(unsigned short u) {
    return __uint_as_float(((unsigned)u) << 16);
}

// ---------------- workspace layout (byte offsets) ----------------
#define XL_OFF    0            // ushort N*192 = 19,200,000
#define XR_OFF    19200000     // ushort N*192
#define WT_OFF    38400000     // short 384*192 = 147,456
#define BLR_OFF   38547456     // float 384
#define PAIR_OFF  38548992     // int2 E = 3,200,000
#define DEG_OFF   41748992     // int N = 200,000
#define SCAN_OFF  41948992     // int N
#define BSUM_OFF  42148992     // int 256
#define BOFF_OFF  42150016     // int 256
#define NB_SCAN ((N_NODES + 255) / 256)   // 196

// ---------------- count (1 atomic/edge) + fused weight pack ----------------
__global__ __launch_bounds__(256) void k_count(const int* __restrict__ ei,
                                               int* __restrict__ deg,
                                               const float* __restrict__ Wl,
                                               const float* __restrict__ Wr,
                                               const float* __restrict__ bl,
                                               const float* __restrict__ br,
                                               short* __restrict__ Wt,
                                               float* __restrict__ blr) {
    int e = blockIdx.x * blockDim.x + threadIdx.x;
    if (e < N_EDGES) atomicAdd(&deg[ei[N_EDGES + e]], 1);
    if (e < 384 * FEAT) {   // pack Wt[n][k] = W[k][n] (bf16)
        int n = e / FEAT, k = e - n * FEAT;
        float v = (n < FEAT) ? Wl[k * FEAT + n] : Wr[k * FEAT + (n - FEAT)];
        Wt[n * FEAT + k] = (short)f2bu(v);
    }
    if (e < 384) blr[e] = (e < FEAT) ? bl[e] : br[e - FEAT];
}

__global__ __launch_bounds__(256) void k_scan1(const int* __restrict__ deg,
                                               int* __restrict__ scan,
                                               int* __restrict__ bsums) {
    int t = threadIdx.x;
    int i = blockIdx.x * 256 + t;
    int v = (i < N_NODES) ? deg[i] : 0;
    __shared__ int s[256];
    s[t] = v; __syncthreads();
    for (int off = 1; off < 256; off <<= 1) {
        int u = (t >= off) ? s[t - off] : 0;
        __syncthreads();
        s[t] += u;
        __syncthreads();
    }
    if (i < N_NODES) scan[i] = s[t];   // inclusive within block
    if (t == 255) bsums[blockIdx.x] = s[255];
}

__global__ __launch_bounds__(256) void k_scan2(int* __restrict__ bsums,
                                               int* __restrict__ boffs) {
    int t = threadIdx.x;
    int v = (t < NB_SCAN) ? bsums[t] : 0;
    __shared__ int s[256];
    s[t] = v; __syncthreads();
    for (int off = 1; off < 256; off <<= 1) {
        int u = (t >= off) ? s[t - off] : 0;
        __syncthreads();
        s[t] += u;
        __syncthreads();
    }
    boffs[t] = s[t] - v;   // exclusive block offsets
}

// ---------------- fused scatter + MFMA GEMM (block-range split) ----------------
#define SCAT_BLOCKS ((N_EDGES + 383) / 384)   // 1042
#define GEMM_BLOCKS (N_NODES / 16)            // 3125
#define OSTRIDE 392   // ushorts per LDS row
__global__ __launch_bounds__(384) void k_scatgemm(const int* __restrict__ ei,
                                                  const float* __restrict__ ew,
                                                  const int* __restrict__ scan,
                                                  const int* __restrict__ boffs,
                                                  int* __restrict__ deg,
                                                  int2* __restrict__ pair,
                                                  const float* __restrict__ x,
                                                  const short* __restrict__ Wt,
                                                  const float* __restrict__ blr,
                                                  unsigned short* __restrict__ xl,
                                                  unsigned short* __restrict__ xr) {
    __shared__ unsigned short sOut[16 * OSTRIDE];
    if (blockIdx.x < SCAT_BLOCKS) {
        int e = blockIdx.x * 384 + threadIdx.x;
        if (e < N_EDGES) {
            int d = ei[N_EDGES + e];
            int inclEnd = boffs[d >> 8] + scan[d];
            int old = atomicSub(&deg[d], 1);     // old in [1, deg]
            int2 p; p.x = ei[e]; p.y = __float_as_int(ew[e]);
            pair[inclEnd - old] = p;
        }
        return;
    }
    int wv   = threadIdx.x >> 6;
    int lane = threadIdx.x & 63;
    int m    = lane & 15;
    int kg   = lane >> 4;            // 0..3
    size_t row0 = (size_t)(blockIdx.x - SCAT_BLOCKS) * 16;
    int ncol0 = wv * 64;

    f32x4 acc0 = {0.f,0.f,0.f,0.f}, acc1 = acc0, acc2 = acc0, acc3 = acc0;

#pragma unroll
    for (int ks = 0; ks < 6; ks++) {
        int kb = ks * 32 + kg * 8;
        const float* ap = x + (row0 + m) * FEAT + kb;
        float4 a0 = *(const float4*)ap;
        float4 a1 = *(const float4*)(ap + 4);
        short8 af;
        af[0] = (short)f2bu(a0.x); af[1] = (short)f2bu(a0.y);
        af[2] = (short)f2bu(a0.z); af[3] = (short)f2bu(a0.w);
        af[4] = (short)f2bu(a1.x); af[5] = (short)f2bu(a1.y);
        af[6] = (short)f2bu(a1.z); af[7] = (short)f2bu(a1.w);
        const short* wp = Wt + (size_t)(ncol0 + m) * FEAT + kb;
        short8 b0 = *(const short8*)(wp);
        short8 b1 = *(const short8*)(wp + 16 * FEAT);
        short8 b2 = *(const short8*)(wp + 32 * FEAT);
        short8 b3 = *(const short8*)(wp + 48 * FEAT);
        acc0 = __builtin_amdgcn_mfma_f32_16x16x32_bf16(af, b0, acc0, 0, 0, 0);
        acc1 = __builtin_amdgcn_mfma_f32_16x16x32_bf16(af, b1, acc1, 0, 0, 0);
        acc2 = __builtin_amdgcn_mfma_f32_16x16x32_bf16(af, b2, acc2, 0, 0, 0);
        acc3 = __builtin_amdgcn_mfma_f32_16x16x32_bf16(af, b3, acc3, 0, 0, 0);
    }

    f32x4 accs[4] = {acc0, acc1, acc2, acc3};
#pragma unroll
    for (int t4 = 0; t4 < 4; t4++) {
        int cc = ncol0 + t4 * 16 + m;
        float bv = blr[cc];
#pragma unroll
        for (int r = 0; r < 4; r++) {
            sOut[(kg * 4 + r) * OSTRIDE + cc] = f2bu(accs[t4][r] + bv);
        }
    }
    __syncthreads();
    for (int q = threadIdx.x; q < 768; q += 384) {
        int row = q / 48, p = q - row * 48;
        uint4 v = *(const uint4*)&sOut[row * OSTRIDE + p * 8];
        if (p < 24) *(uint4*)(xl + (row0 + row) * FEAT + p * 8) = v;
        else        *(uint4*)(xr + (row0 + row) * FEAT + (p - 24) * 8) = v;
    }
}

// ---------------- fused node kernel ----------------
// 8 nodes/block; double-buffered LDS edge-row staging; alpha reads b128;
// att/We held in per-thread registers (fixed head per thread) -> no LDS conflicts;
// accumulate uses plain word layout (conflict-free, pair-broadcast).
#define NPB 8
#define CEDGE 32
#define RS 100   // uints per row; 100 % 32 = 4 spreads row bases across banks
__global__ __launch_bounds__(192) void k_node(const float* __restrict__ x,
                                              const float* __restrict__ bias,
                                              const float* __restrict__ att,
                                              const float* __restrict__ We,
                                              const int* __restrict__ scan,
                                              const int* __restrict__ boffs,
                                              const int2* __restrict__ pair,
                                              const unsigned short* __restrict__ xl,
                                              const unsigned short* __restrict__ xr,
                                              float* __restrict__ out) {
    __shared__ __align__(16) unsigned int sXL[2][CEDGE * RS];
    __shared__ __align__(16) unsigned int sXR[NPB * RS];
    __shared__ __align__(16) unsigned int sXS[NPB * RS];
    __shared__ float sEx[CEDGE * HEADS];
    __shared__ float sExS[NPB * HEADS];
    __shared__ float sW[2][CEDGE];
    __shared__ int   sDst[2][CEDGE];
    __shared__ int   sStart[NPB + 1];

    int t = threadIdx.x;
    int h = t >> 5;                  // head for channel role
    int n0 = blockIdx.x * NPB;
    int hhA = t % HEADS;             // head for alpha role (fixed per thread)

    // register att/We slice for the alpha role: zero LDS traffic
    float rAtt[DIMS], rWe[DIMS];
#pragma unroll
    for (int c = 0; c < DIMS; c++) { rAtt[c] = att[hhA * DIMS + c]; rWe[c] = We[hhA * DIMS + c]; }

    if (t <= NPB) {   // exclusive starts from scan/boffs
        int n = n0 + t;
        int st;
        if (n >= N_NODES) st = N_EDGES;
        else {
            int b = n >> 8;
            st = boffs[b] + ((n & 255) ? scan[n - 1] : 0);
        }
        sStart[t] = st;
    }
    {   // stage this block's 8 xr + 8 xl(self) rows: 192 = 8 rows x 24 uint4
        int nn = t / 24, p = t - nn * 24;
        *(uint4*)&sXR[nn * RS + p * 4] = ((const uint4*)(xr + (size_t)(n0 + nn) * FEAT))[p];
        *(uint4*)&sXS[nn * RS + p * 4] = ((const uint4*)(xl + (size_t)(n0 + nn) * FEAT))[p];
    }
    __syncthreads();

    int gbase = sStart[0];
    int etot = sStart[NPB] - gbase;
    int nchunk = (etot + CEDGE - 1) / CEDGE;
    float acc[NPB], den[NPB], wsm[NPB];
#pragma unroll
    for (int nn = 0; nn < NPB; nn++) { acc[nn] = 0.f; den[nn] = 0.f; wsm[nn] = 0.f; }

    const int* pix = (const int*)pair;   // flat int view

    auto stage = [&](int bn, int i0n) {
        int cn = etot - i0n; if (cn > CEDGE) cn = CEDGE;
        int g0 = gbase + i0n;
        int nld = cn * 24;
#pragma unroll
        for (int s = 0; s < 4; s++) {
            int q = t + s * 192;
            if (q < nld) {
                int i = q / 24, p = q - i * 24;
                int src = pix[2 * (g0 + i)];   // redundant L1-hit load (kills a barrier)
                *(uint4*)&sXL[bn][i * RS + p * 4] =
                    *(const uint4*)(xl + (size_t)src * FEAT + p * 8);
            }
        }
        if (t < cn) sW[bn][t] = __int_as_float(pix[2 * (g0 + t) + 1]);
        if (t < NPB) {
            int lo = sStart[t] - g0;     if (lo < 0) lo = 0;
            int hi = sStart[t + 1] - g0; if (hi > cn) hi = cn;
            for (int q = lo; q < hi; q++) sDst[bn][q] = t;
        }
    };

    if (nchunk > 0) stage(0, 0);
    __syncthreads();

    for (int k = 0; k < nchunk; k++) {
        int b = k & 1;
        int i0 = k * CEDGE;
        int c = etot - i0; if (c > CEDGE) c = CEDGE;

        // ---- alpha + exp: thread per (edge, head); b128 LDS reads, register att/We
        if (t < c * HEADS) {
            int i = t / HEADS;
            int nn = sDst[b][i];
            float w = sW[b][i];
            const uint4* pa = (const uint4*)&sXL[b][i * RS + hhA * 16];
            const uint4* pb = (const uint4*)&sXR[nn * RS + hhA * 16];
            float alpha = 0.f;
#pragma unroll
            for (int g = 0; g < 4; g++) {
                uint4 a4 = pa[g];
                uint4 b4 = pb[g];
                unsigned aw[4] = {a4.x, a4.y, a4.z, a4.w};
                unsigned bw[4] = {b4.x, b4.y, b4.z, b4.w};
#pragma unroll
                for (int q = 0; q < 4; q++) {
                    int c0 = g * 8 + q * 2;
                    float m0 = bu2f((unsigned short)aw[q]) + bu2f((unsigned short)bw[q]) + w * rWe[c0];
                    m0 = (m0 > 0.f) ? m0 : NEG_SLOPE * m0;
                    alpha += m0 * rAtt[c0];
                    float m1 = bu2f((unsigned short)(aw[q] >> 16)) + bu2f((unsigned short)(bw[q] >> 16)) + w * rWe[c0 + 1];
                    m1 = (m1 > 0.f) ? m1 : NEG_SLOPE * m1;
                    alpha += m1 * rAtt[c0 + 1];
                }
            }
            sEx[t] = __expf(alpha);
        }
        __syncthreads();   // sEx ready (LDS-only drain, cheap)

        // ---- issue next chunk's staging loads, then overlap with accumulate
        if (k + 1 < nchunk) stage(1 - b, i0 + CEDGE);

        // ---- accumulate: thread per channel; plain word layout = conflict-free
        {
            int cw = t >> 1;
#pragma unroll
            for (int nn = 0; nn < NPB; nn++) {
                int lo = sStart[nn] - gbase - i0;     if (lo < 0) lo = 0;
                int hi = sStart[nn + 1] - gbase - i0; if (hi > c) hi = c;
                for (int i = lo; i < hi; i++) {
                    float ex = sEx[i * HEADS + h];
                    unsigned u = sXL[b][i * RS + cw];
                    unsigned short v = (t & 1) ? (unsigned short)(u >> 16) : (unsigned short)u;
                    acc[nn] += ex * bu2f(v);
                    den[nn] += ex;
                    wsm[nn] += sW[b][i];
                }
            }
        }
        __syncthreads();   // staging visible; sEx/sW/sDst[1-b] free for next phase
    }

    // ---- self-loop alpha (w = mean incoming weight), register att/We
    if (t < NPB * HEADS) {
        int nn = t / HEADS;              // hhA == t % HEADS matches register slice
        int dg = sStart[nn + 1] - sStart[nn];
        float w = wsm[nn] / fmaxf((float)dg, 1.0f);
        const uint4* pa = (const uint4*)&sXS[nn * RS + hhA * 16];
        const uint4* pb = (const uint4*)&sXR[nn * RS + hhA * 16];
        float alpha = 0.f;
#pragma unroll
        for (int g = 0; g < 4; g++) {
            uint4 a4 = pa[g];
            uint4 b4 = pb[g];
            unsigned aw[4] = {a4.x, a4.y, a4.z, a4.w};
            unsigned bw[4] = {b4.x, b4.y, b4.z, b4.w};
#pragma unroll
            for (int q = 0; q < 4; q++) {
                int c0 = g * 8 + q * 2;
                float m0 = bu2f((unsigned short)aw[q]) + bu2f((unsigned short)bw[q]) + w * rWe[c0];
                m0 = (m0 > 0.f) ? m0 : NEG_SLOPE * m0;
                alpha += m0 * rAtt[c0];
                float m1 = bu2f((unsigned short)(aw[q] >> 16)) + bu2f((unsigned short)(bw[q] >> 16)) + w * rWe[c0 + 1];
                m1 = (m1 > 0.f) ? m1 : NEG_SLOPE * m1;
                alpha += m1 * rAtt[c0 + 1];
            }
        }
        sExS[t] = __expf(alpha);
    }
    __syncthreads();

    // ---- epilogue: self-loop add, divide, residual + bias + relu
    float bj = bias[t];
    int cw = t >> 1;
#pragma unroll
    for (int nn = 0; nn < NPB; nn++) {
        float exS = sExS[nn * HEADS + h];
        unsigned u = sXS[nn * RS + cw];
        unsigned short v = (t & 1) ? (unsigned short)(u >> 16) : (unsigned short)u;
        float num = acc[nn] + exS * bu2f(v);
        float dn  = den[nn] + exS;
        size_t off = (size_t)(n0 + nn) * FEAT + t;
        float val = x[off] + bj + num / dn;
        out[off] = (val > 0.f) ? val : 0.f;
    }
}

extern "C" void kernel_launch(void* const* d_in, const int* in_sizes, int n_in,
                              void* d_out, int out_size, void* d_ws, size_t ws_size,
                              hipStream_t stream) {
    const float* x    = (const float*)d_in[0];
    const int*   ei   = (const int*)d_in[1];
    const float* ew   = (const float*)d_in[2];
    const float* Wl   = (const float*)d_in[3];
    const float* bl   = (const float*)d_in[4];
    const float* Wr   = (const float*)d_in[5];
    const float* br   = (const float*)d_in[6];
    const float* We   = (const float*)d_in[7];
    const float* att  = (const float*)d_in[8];
    const float* bias = (const float*)d_in[9];
    float* out = (float*)d_out;

    char* ws = (char*)d_ws;
    unsigned short* xl = (unsigned short*)(ws + XL_OFF);
    unsigned short* xr = (unsigned short*)(ws + XR_OFF);
    short* Wt     = (short*)(ws + WT_OFF);
    float* blr    = (float*)(ws + BLR_OFF);
    int2*  pair   = (int2*)(ws + PAIR_OFF);
    int*   deg    = (int*)(ws + DEG_OFF);
    int*   scan   = (int*)(ws + SCAN_OFF);
    int*   bsums  = (int*)(ws + BSUM_OFF);
    int*   boffs  = (int*)(ws + BOFF_OFF);

    // zero deg; harness poisons ws with 0xAA
    hipMemsetAsync(ws + DEG_OFF, 0, N_NODES * sizeof(int), stream);

    k_count<<<(N_EDGES + 255) / 256, 256, 0, stream>>>(ei, deg, Wl, Wr, bl, br, Wt, blr);
    k_scan1<<<NB_SCAN, 256, 0, stream>>>(deg, scan, bsums);
    k_scan2<<<1, 256, 0, stream>>>(bsums, boffs);

    k_scatgemm<<<SCAT_BLOCKS + GEMM_BLOCKS, 384, 0, stream>>>(ei, ew, scan, boffs, deg,
                                                              pair, x, Wt, blr, xl, xr);

    k_node<<<N_NODES / NPB, 192, 0, stream>>>(x, bias, att, We, scan, boffs,
                                              pair, xl, xr, out);
}

// Round 11
// 283.456 us; speedup vs baseline: 1.5211x; 1.5211x over previous
//
#include <hip/hip_runtime.h>
#include <hip/hip_bf16.h>
#include <math.h>

#define N_NODES 50000
#define N_EDGES 400000
#define HEADS 6
#define DIMS 32
#define FEAT 192
#define NEG_SLOPE 0.2f

typedef __attribute__((ext_vector_type(8))) short short8;
typedef __attribute__((ext_vector_type(4))) float f32x4;

__device__ __forceinline__ unsigned short f2bu(float f) {
    __hip_bfloat16 h = __float2bfloat16(f);
    unsigned short u; __builtin_memcpy(&u, &h, 2); return u;
}
__device__ __forceinline__ float bu2f(unsigned short u) {
    return __uint_as_float(((unsigned)u) << 16);
}

// ---------------- workspace layout (byte offsets) ----------------
#define XL_OFF    0            // ushort N*192 = 19,200,000
#define XR_OFF    19200000     // ushort N*192
#define WT_OFF    38400000     // short 384*192 = 147,456
#define BLR_OFF   38547456     // float 384
#define PAIR_OFF  38548992     // int2 E = 3,200,000
#define DEG_OFF   41748992     // int N = 200,000
#define SCAN_OFF  41948992     // int N
#define BSUM_OFF  42148992     // int 256
#define BOFF_OFF  42150016     // int 256
#define NB_SCAN ((N_NODES + 255) / 256)   // 196

// ---------------- count (1 atomic/edge) + fused weight pack ----------------
__global__ __launch_bounds__(256) void k_count(const int* __restrict__ ei,
                                               int* __restrict__ deg,
                                               const float* __restrict__ Wl,
                                               const float* __restrict__ Wr,
                                               const float* __restrict__ bl,
                                               const float* __restrict__ br,
                                               short* __restrict__ Wt,
                                               float* __restrict__ blr) {
    int e = blockIdx.x * blockDim.x + threadIdx.x;
    if (e < N_EDGES) atomicAdd(&deg[ei[N_EDGES + e]], 1);
    if (e < 384 * FEAT) {   // pack Wt[n][k] = W[k][n] (bf16)
        int n = e / FEAT, k = e - n * FEAT;
        float v = (n < FEAT) ? Wl[k * FEAT + n] : Wr[k * FEAT + (n - FEAT)];
        Wt[n * FEAT + k] = (short)f2bu(v);
    }
    if (e < 384) blr[e] = (e < FEAT) ? bl[e] : br[e - FEAT];
}

__global__ __launch_bounds__(256) void k_scan1(const int* __restrict__ deg,
                                               int* __restrict__ scan,
                                               int* __restrict__ bsums) {
    int t = threadIdx.x;
    int i = blockIdx.x * 256 + t;
    int v = (i < N_NODES) ? deg[i] : 0;
    __shared__ int s[256];
    s[t] = v; __syncthreads();
    for (int off = 1; off < 256; off <<= 1) {
        int u = (t >= off) ? s[t - off] : 0;
        __syncthreads();
        s[t] += u;
        __syncthreads();
    }
    if (i < N_NODES) scan[i] = s[t];   // inclusive within block
    if (t == 255) bsums[blockIdx.x] = s[255];
}

__global__ __launch_bounds__(256) void k_scan2(int* __restrict__ bsums,
                                               int* __restrict__ boffs) {
    int t = threadIdx.x;
    int v = (t < NB_SCAN) ? bsums[t] : 0;
    __shared__ int s[256];
    s[t] = v; __syncthreads();
    for (int off = 1; off < 256; off <<= 1) {
        int u = (t >= off) ? s[t - off] : 0;
        __syncthreads();
        s[t] += u;
        __syncthreads();
    }
    boffs[t] = s[t] - v;   // exclusive block offsets
}

// ---------------- fused scatter + MFMA GEMM (block-range split) ----------------
// GEMM stages the 16-row x tile in LDS as bf16 ONCE per block (x read 1x, not 6x).
#define SCAT_BLOCKS ((N_EDGES + 383) / 384)   // 1042
#define GEMM_BLOCKS (N_NODES / 16)            // 3125
#define OSTRIDE 392   // ushorts per LDS row (epilogue)
#define ASTRIDE 200   // ushorts per A-tile row (16B-aligned rows; XOR-swizzled k blocks)
__global__ __launch_bounds__(384) void k_scatgemm(const int* __restrict__ ei,
                                                  const float* __restrict__ ew,
                                                  const int* __restrict__ scan,
                                                  const int* __restrict__ boffs,
                                                  int* __restrict__ deg,
                                                  int2* __restrict__ pair,
                                                  const float* __restrict__ x,
                                                  const short* __restrict__ Wt,
                                                  const float* __restrict__ blr,
                                                  unsigned short* __restrict__ xl,
                                                  unsigned short* __restrict__ xr) {
    __shared__ unsigned short sOut[16 * OSTRIDE];
    __shared__ unsigned short sA[16 * ASTRIDE];
    if (blockIdx.x < SCAT_BLOCKS) {
        int e = blockIdx.x * 384 + threadIdx.x;
        if (e < N_EDGES) {
            int d = ei[N_EDGES + e];
            int inclEnd = boffs[d >> 8] + scan[d];
            int old = atomicSub(&deg[d], 1);     // old in [1, deg]
            int2 p; p.x = ei[e]; p.y = __float_as_int(ew[e]);
            pair[inclEnd - old] = p;
        }
        return;
    }
    size_t row0 = (size_t)(blockIdx.x - SCAT_BLOCKS) * 16;

    // ---- stage A tile: 16 rows x 192 floats -> bf16 in LDS (384 thr x 8 floats)
    {
        int q = threadIdx.x;              // segment of 8 floats
        int row = q / 24, k0 = (q - row * 24) * 8;
        const float* ap = x + (row0 + row) * FEAT + k0;
        float4 v0 = *(const float4*)ap;
        float4 v1 = *(const float4*)(ap + 4);
        unsigned short tmp[8];
        tmp[0] = f2bu(v0.x); tmp[1] = f2bu(v0.y); tmp[2] = f2bu(v0.z); tmp[3] = f2bu(v0.w);
        tmp[4] = f2bu(v1.x); tmp[5] = f2bu(v1.y); tmp[6] = f2bu(v1.z); tmp[7] = f2bu(v1.w);
        int kw = (k0 >> 1) ^ ((row & 7) << 2);   // word offset with XOR swizzle
        *(uint4*)&sA[row * ASTRIDE + kw * 2] = *(const uint4*)tmp;
    }
    __syncthreads();

    int wv   = threadIdx.x >> 6;
    int lane = threadIdx.x & 63;
    int m    = lane & 15;
    int kg   = lane >> 4;            // 0..3
    int ncol0 = wv * 64;

    f32x4 acc0 = {0.f,0.f,0.f,0.f}, acc1 = acc0, acc2 = acc0, acc3 = acc0;

#pragma unroll
    for (int ks = 0; ks < 6; ks++) {
        int kb = ks * 32 + kg * 8;
        int kw = (kb >> 1) ^ ((m & 7) << 2);
        short8 af = *(const short8*)&sA[m * ASTRIDE + kw * 2];
        const short* wp = Wt + (size_t)(ncol0 + m) * FEAT + kb;
        short8 b0 = *(const short8*)(wp);
        short8 b1 = *(const short8*)(wp + 16 * FEAT);
        short8 b2 = *(const short8*)(wp + 32 * FEAT);
        short8 b3 = *(const short8*)(wp + 48 * FEAT);
        acc0 = __builtin_amdgcn_mfma_f32_16x16x32_bf16(af, b0, acc0, 0, 0, 0);
        acc1 = __builtin_amdgcn_mfma_f32_16x16x32_bf16(af, b1, acc1, 0, 0, 0);
        acc2 = __builtin_amdgcn_mfma_f32_16x16x32_bf16(af, b2, acc2, 0, 0, 0);
        acc3 = __builtin_amdgcn_mfma_f32_16x16x32_bf16(af, b3, acc3, 0, 0, 0);
    }

    f32x4 accs[4] = {acc0, acc1, acc2, acc3};
#pragma unroll
    for (int t4 = 0; t4 < 4; t4++) {
        int cc = ncol0 + t4 * 16 + m;
        float bv = blr[cc];
#pragma unroll
        for (int r = 0; r < 4; r++) {
            sOut[(kg * 4 + r) * OSTRIDE + cc] = f2bu(accs[t4][r] + bv);
        }
    }
    __syncthreads();
    for (int q = threadIdx.x; q < 768; q += 384) {
        int row = q / 48, p = q - row * 48;
        uint4 v = *(const uint4*)&sOut[row * OSTRIDE + p * 8];
        if (p < 24) *(uint4*)(xl + (row0 + row) * FEAT + p * 8) = v;
        else        *(uint4*)(xr + (row0 + row) * FEAT + (p - 24) * 8) = v;
    }
}

// ---------------- fused node kernel (round-8 flow) ----------------
// 8 nodes/block; single-buffer LDS staging; b128 alpha reads;
// att/We in LDS with padded stride 33: head hh's slice starts at bank hh -> the
// six heads read 6 distinct banks per channel (kills the 6-way broadcast conflict).
#define NPB 8
#define CEDGE 32
#define RS 100   // uints per row; 100 % 32 = 4 spreads row bases across banks
__global__ __launch_bounds__(192) void k_node(const float* __restrict__ x,
                                              const float* __restrict__ bias,
                                              const float* __restrict__ att,
                                              const float* __restrict__ We,
                                              const int* __restrict__ scan,
                                              const int* __restrict__ boffs,
                                              const int2* __restrict__ pair,
                                              const unsigned short* __restrict__ xl,
                                              const unsigned short* __restrict__ xr,
                                              float* __restrict__ out) {
    __shared__ __align__(16) unsigned int sXL[CEDGE * RS];
    __shared__ __align__(16) unsigned int sXR[NPB * RS];
    __shared__ __align__(16) unsigned int sXS[NPB * RS];
    __shared__ float sEx[CEDGE * HEADS];
    __shared__ float sExS[NPB * HEADS];
    __shared__ int   sSrc[CEDGE];
    __shared__ float sW[CEDGE];
    __shared__ int   sDst[CEDGE];
    __shared__ int   sStart[NPB + 1];
    __shared__ float sAttP[HEADS * 33], sWeP[HEADS * 33];   // padded: [hh*33 + c]

    int t = threadIdx.x;
    int h = t >> 5;                  // head for channel role
    int n0 = blockIdx.x * NPB;

    for (int q = t; q < HEADS * 33; q += 192) {
        int hh = q / 33, c = q - hh * 33;
        if (c < 32) { sAttP[q] = att[hh * 32 + c]; sWeP[q] = We[hh * 32 + c]; }
    }
    if (t <= NPB) {   // exclusive starts from scan/boffs
        int n = n0 + t;
        int st;
        if (n >= N_NODES) st = N_EDGES;
        else {
            int b = n >> 8;
            st = boffs[b] + ((n & 255) ? scan[n - 1] : 0);
        }
        sStart[t] = st;
    }
    {   // stage this block's 8 xr + 8 xl(self) rows: 192 = 8 rows x 24 uint4
        int nn = t / 24, p = t - nn * 24;
        *(uint4*)&sXR[nn * RS + p * 4] = ((const uint4*)(xr + (size_t)(n0 + nn) * FEAT))[p];
        *(uint4*)&sXS[nn * RS + p * 4] = ((const uint4*)(xl + (size_t)(n0 + nn) * FEAT))[p];
    }
    __syncthreads();

    int gbase = sStart[0];
    int etot = sStart[NPB] - gbase;
    float acc[NPB], den[NPB], wsm[NPB];
#pragma unroll
    for (int nn = 0; nn < NPB; nn++) { acc[nn] = 0.f; den[nn] = 0.f; wsm[nn] = 0.f; }

    for (int i0 = 0; i0 < etot; i0 += CEDGE) {
        int c = etot - i0; if (c > CEDGE) c = CEDGE;
        if (t < c) {
            int2 p = pair[gbase + i0 + t];
            sSrc[t] = p.x;
            sW[t] = __int_as_float(p.y);
        }
        if (t < NPB) {   // per-edge local dst index
            int lo = sStart[t] - gbase - i0;     if (lo < 0) lo = 0;
            int hi = sStart[t + 1] - gbase - i0; if (hi > c) hi = c;
            for (int q = lo; q < hi; q++) sDst[q] = t;
        }
        __syncthreads();
        // stage xl rows; MLP 4
        int nld = c * 24;
#pragma unroll
        for (int s = 0; s < 4; s++) {
            int q = t + s * 192;
            if (q < nld) {
                int i = q / 24, p = q - i * 24;
                *(uint4*)&sXL[i * RS + p * 4] =
                    *(const uint4*)(xl + (size_t)sSrc[i] * FEAT + p * 8);
            }
        }
        __syncthreads();
        // alpha + exp: thread per (edge, head); b128 LDS reads; padded att/We
        if (t < c * HEADS) {
            int i = t / HEADS, hh = t - i * HEADS;
            int nn = sDst[i];
            float w = sW[i];
            const uint4* pa = (const uint4*)&sXL[i * RS + hh * 16];
            const uint4* pb = (const uint4*)&sXR[nn * RS + hh * 16];
            float alpha = 0.f;
#pragma unroll
            for (int g = 0; g < 4; g++) {
                uint4 a4 = pa[g];
                uint4 b4 = pb[g];
                unsigned aw[4] = {a4.x, a4.y, a4.z, a4.w};
                unsigned bw[4] = {b4.x, b4.y, b4.z, b4.w};
#pragma unroll
                for (int q = 0; q < 4; q++) {
                    int c0 = g * 8 + q * 2;
                    float m0 = bu2f((unsigned short)aw[q]) + bu2f((unsigned short)bw[q]) + w * sWeP[hh * 33 + c0];
                    m0 = (m0 > 0.f) ? m0 : NEG_SLOPE * m0;
                    alpha += m0 * sAttP[hh * 33 + c0];
                    float m1 = bu2f((unsigned short)(aw[q] >> 16)) + bu2f((unsigned short)(bw[q] >> 16)) + w * sWeP[hh * 33 + c0 + 1];
                    m1 = (m1 > 0.f) ? m1 : NEG_SLOPE * m1;
                    alpha += m1 * sAttP[hh * 33 + c0 + 1];
                }
            }
            sEx[t] = __expf(alpha);
        }
        __syncthreads();
        // accumulate: thread per channel; plain word layout = pair-broadcast, conflict-free
        {
            int cw = t >> 1;
#pragma unroll
            for (int nn = 0; nn < NPB; nn++) {
                int lo = sStart[nn] - gbase - i0;     if (lo < 0) lo = 0;
                int hi = sStart[nn + 1] - gbase - i0; if (hi > c) hi = c;
                for (int i = lo; i < hi; i++) {
                    float ex = sEx[i * HEADS + h];
                    unsigned u = sXL[i * RS + cw];
                    unsigned short v = (t & 1) ? (unsigned short)(u >> 16) : (unsigned short)u;
                    acc[nn] += ex * bu2f(v);
                    den[nn] += ex;
                    wsm[nn] += sW[i];
                }
            }
        }
        __syncthreads();
    }

    // self-loop alpha (w = mean incoming weight)
    if (t < NPB * HEADS) {
        int nn = t / HEADS, hh = t - nn * HEADS;
        int dg = sStart[nn + 1] - sStart[nn];
        float w = wsm[nn] / fmaxf((float)dg, 1.0f);
        const uint4* pa = (const uint4*)&sXS[nn * RS + hh * 16];
        const uint4* pb = (const uint4*)&sXR[nn * RS + hh * 16];
        float alpha = 0.f;
#pragma unroll
        for (int g = 0; g < 4; g++) {
            uint4 a4 = pa[g];
            uint4 b4 = pb[g];
            unsigned aw[4] = {a4.x, a4.y, a4.z, a4.w};
            unsigned bw[4] = {b4.x, b4.y, b4.z, b4.w};
#pragma unroll
            for (int q = 0; q < 4; q++) {
                int c0 = g * 8 + q * 2;
                float m0 = bu2f((unsigned short)aw[q]) + bu2f((unsigned short)bw[q]) + w * sWeP[hh * 33 + c0];
                m0 = (m0 > 0.f) ? m0 : NEG_SLOPE * m0;
                alpha += m0 * sAttP[hh * 33 + c0];
                float m1 = bu2f((unsigned short)(aw[q] >> 16)) + bu2f((unsigned short)(bw[q] >> 16)) + w * sWeP[hh * 33 + c0 + 1];
                m1 = (m1 > 0.f) ? m1 : NEG_SLOPE * m1;
                alpha += m1 * sAttP[hh * 33 + c0 + 1];
            }
        }
        sExS[t] = __expf(alpha);
    }
    __syncthreads();

    // epilogue: self-loop add, divide, residual + bias + relu
    float bj = bias[t];
    int cw = t >> 1;
#pragma unroll
    for (int nn = 0; nn < NPB; nn++) {
        float exS = sExS[nn * HEADS + h];
        unsigned u = sXS[nn * RS + cw];
        unsigned short v = (t & 1) ? (unsigned short)(u >> 16) : (unsigned short)u;
        float num = acc[nn] + exS * bu2f(v);
        float dn  = den[nn] + exS;
        size_t off = (size_t)(n0 + nn) * FEAT + t;
        float val = x[off] + bj + num / dn;
        out[off] = (val > 0.f) ? val : 0.f;
    }
}

extern "C" void kernel_launch(void* const* d_in, const int* in_sizes, int n_in,
                              void* d_out, int out_size, void* d_ws, size_t ws_size,
                              hipStream_t stream) {
    const float* x    = (const float*)d_in[0];
    const int*   ei   = (const int*)d_in[1];
    const float* ew   = (const float*)d_in[2];
    const float* Wl   = (const float*)d_in[3];
    const float* bl   = (const float*)d_in[4];
    const float* Wr   = (const float*)d_in[5];
    const float* br   = (const float*)d_in[6];
    const float* We   = (const float*)d_in[7];
    const float* att  = (const float*)d_in[8];
    const float* bias = (const float*)d_in[9];
    float* out = (float*)d_out;

    char* ws = (char*)d_ws;
    unsigned short* xl = (unsigned short*)(ws + XL_OFF);
    unsigned short* xr = (unsigned short*)(ws + XR_OFF);
    short* Wt     = (short*)(ws + WT_OFF);
    float* blr    = (float*)(ws + BLR_OFF);
    int2*  pair   = (int2*)(ws + PAIR_OFF);
    int*   deg    = (int*)(ws + DEG_OFF);
    int*   scan   = (int*)(ws + SCAN_OFF);
    int*   bsums  = (int*)(ws + BSUM_OFF);
    int*   boffs  = (int*)(ws + BOFF_OFF);

    // zero deg; harness poisons ws with 0xAA
    hipMemsetAsync(ws + DEG_OFF, 0, N_NODES * sizeof(int), stream);

    k_count<<<(N_EDGES + 255) / 256, 256, 0, stream>>>(ei, deg, Wl, Wr, bl, br, Wt, blr);
    k_scan1<<<NB_SCAN, 256, 0, stream>>>(deg, scan, bsums);
    k_scan2<<<1, 256, 0, stream>>>(bsums, boffs);

    k_scatgemm<<<SCAT_BLOCKS + GEMM_BLOCKS, 384, 0, stream>>>(ei, ew, scan, boffs, deg,
                                                              pair, x, Wt, blr, xl, xr);

    k_node<<<N_NODES / NPB, 192, 0, stream>>>(x, bias, att, We, scan, boffs,
                                              pair, xl, xr, out);
}